// Round 4
// baseline (744.753 us; speedup 1.0000x reference)
//
#include <hip/hip_runtime.h>
#include <cmath>

#define B 256
#define N0 512
#define F0 128
#define H 32
#define NC 16

// ---------------- x @ w1 -> h (optionally scattered) ; x @ w2 + b -> g ----------------
// block 256 = 8 h-threads (x4 h) x 32 row-groups (xRPT rows)
template<int F, int RPT, int NPB, bool SCATTER>
__global__ __launch_bounds__(256) void k_xw(
    const float* __restrict__ x, const float* __restrict__ w1,
    const float* __restrict__ w2, const float* __restrict__ bias,
    const int* __restrict__ sidx,
    float* __restrict__ h, float* __restrict__ g) {
  __shared__ float w1t[H][F + 4];
  __shared__ float w2t[H][F + 4];
  __shared__ float bs[H];
  const int tid = threadIdx.x;
  for (int i = tid; i < F * H; i += 256) {
    int f = i >> 5, hc = i & 31;
    w1t[hc][f] = w1[i];
    w2t[hc][f] = w2[i];
  }
  if (tid < H) bs[tid] = bias[tid];
  __syncthreads();
  const int hq = tid & 7;
  const int rq = tid >> 3;
  const size_t row0 = (size_t)blockIdx.x * (32 * RPT) + (size_t)rq * RPT;
  const float* xb = x + row0 * F;
  float acc1[RPT][4];
  float acc2[RPT][4];
  #pragma unroll
  for (int r = 0; r < RPT; ++r)
    for (int c = 0; c < 4; ++c) { acc1[r][c] = 0.f; acc2[r][c] = 0.f; }
  for (int f0 = 0; f0 < F; f0 += 4) {
    float4 w1v[4], w2v[4];
    #pragma unroll
    for (int hh = 0; hh < 4; ++hh) {
      w1v[hh] = *(const float4*)&w1t[hq * 4 + hh][f0];
      w2v[hh] = *(const float4*)&w2t[hq * 4 + hh][f0];
    }
    #pragma unroll
    for (int r = 0; r < RPT; ++r) {
      float4 xv = *(const float4*)(xb + (size_t)r * F + f0);
      #pragma unroll
      for (int hh = 0; hh < 4; ++hh) {
        acc1[r][hh] += xv.x * w1v[hh].x + xv.y * w1v[hh].y + xv.z * w1v[hh].z + xv.w * w1v[hh].w;
        acc2[r][hh] += xv.x * w2v[hh].x + xv.y * w2v[hh].y + xv.z * w2v[hh].z + xv.w * w2v[hh].w;
      }
    }
  }
  #pragma unroll
  for (int r = 0; r < RPT; ++r) {
    size_t row = row0 + r;
    size_t go = row * H + hq * 4;
    size_t ho;
    if (SCATTER) {
      int b = (int)(row / NPB);
      int gid = sidx[row];
      ho = ((size_t)b * N0 + gid) * H + hq * 4;
    } else {
      ho = go;
    }
    float4 hv = make_float4(acc1[r][0], acc1[r][1], acc1[r][2], acc1[r][3]);
    float4 gv = make_float4(acc2[r][0] + bs[hq * 4 + 0], acc2[r][1] + bs[hq * 4 + 1],
                            acc2[r][2] + bs[hq * 4 + 2], acc2[r][3] + bs[hq * 4 + 3]);
    *(float4*)(h + ho) = hv;
    *(float4*)(g + go) = gv;
  }
}

// ---------------- out = relu(A[rid,:] @ hf + g) ; K always = N0 (hf zero-padded) ----------
// Software-pipelined: global->reg prefetch of chunk c+1 overlaps compute of chunk c.
// a-tile stride 68 floats -> aligned b128 reads (4-way bank alias, ~1.58x, acceptable).
// block 256 = 8 hq x 32 rq; rows/block = 32*RPT.
template<int NROW, int RPT>
__global__ __launch_bounds__(256) void k_amm(
    const float* __restrict__ a0, const int* __restrict__ rid,
    const float* __restrict__ hf, const float* __restrict__ gbuf,
    float* __restrict__ out) {
  constexpr int RB = 32 * RPT;     // rows per block
  constexpr int JC = 64;           // j per chunk
  constexpr int AS = JC + 4;       // 68: b128-aligned padded stride
  constexpr int AI = RB / 16;      // float4 a-loads per thread per chunk
  constexpr int HI = JC * H / 4 / 256;  // float4 h-loads per thread per chunk (=2)
  __shared__ float atile[RB][AS];
  __shared__ float htile[JC][H];
  __shared__ int rowid[RB];
  const int tid = threadIdx.x;
  const int b = blockIdx.x;
  const int row0 = blockIdx.y * RB;
  for (int i = tid; i < RB; i += 256) {
    int row = row0 + i;
    rowid[i] = rid ? rid[(size_t)b * NROW + row] : row;
  }
  __syncthreads();
  const int hq = tid & 7;
  const int rq = tid >> 3;
  const int ar = tid >> 4;   // staging row-sub (0..15)
  const int ac = tid & 15;   // staging f4-col (0..15) => 16x16B = 256B per row-seg
  const float* abase = a0 + (size_t)b * N0 * N0;
  const float4* hsrc = (const float4*)(hf + (size_t)b * N0 * H);
  float4 abuf[AI], hbuf[HI];
  // prefetch chunk 0
  #pragma unroll
  for (int i = 0; i < AI; ++i)
    abuf[i] = *(const float4*)(abase + (size_t)rowid[ar + i * 16] * N0 + ac * 4);
  #pragma unroll
  for (int i = 0; i < HI; ++i) hbuf[i] = hsrc[tid + i * 256];
  float acc[RPT][4];
  #pragma unroll
  for (int r = 0; r < RPT; ++r) { acc[r][0] = acc[r][1] = acc[r][2] = acc[r][3] = 0.f; }
  for (int c = 0; c < N0 / JC; ++c) {
    // write staged chunk c to LDS
    #pragma unroll
    for (int i = 0; i < AI; ++i)
      *(float4*)&atile[ar + i * 16][ac * 4] = abuf[i];
    #pragma unroll
    for (int i = 0; i < HI; ++i) ((float4*)htile)[tid + i * 256] = hbuf[i];
    __syncthreads();
    // issue global loads for chunk c+1 (land in regs during compute)
    if (c + 1 < N0 / JC) {
      const int j0 = (c + 1) * JC;
      #pragma unroll
      for (int i = 0; i < AI; ++i)
        abuf[i] = *(const float4*)(abase + (size_t)rowid[ar + i * 16] * N0 + j0 + ac * 4);
      #pragma unroll
      for (int i = 0; i < HI; ++i) hbuf[i] = hsrc[j0 * (H / 4) + tid + i * 256];
    }
    // compute chunk c
    #pragma unroll
    for (int j = 0; j < JC; j += 4) {
      float4 hv[4];
      #pragma unroll
      for (int jj = 0; jj < 4; ++jj) hv[jj] = *(const float4*)&htile[j + jj][hq * 4];
      #pragma unroll
      for (int r = 0; r < RPT; ++r) {
        float4 av = *(const float4*)&atile[rq * RPT + r][j];
        acc[r][0] += av.x * hv[0].x + av.y * hv[1].x + av.z * hv[2].x + av.w * hv[3].x;
        acc[r][1] += av.x * hv[0].y + av.y * hv[1].y + av.z * hv[2].y + av.w * hv[3].y;
        acc[r][2] += av.x * hv[0].z + av.y * hv[1].z + av.z * hv[2].z + av.w * hv[3].z;
        acc[r][3] += av.x * hv[0].w + av.y * hv[1].w + av.z * hv[2].w + av.w * hv[3].w;
      }
    }
    __syncthreads();
  }
  #pragma unroll
  for (int r = 0; r < RPT; ++r) {
    int row = row0 + rq * RPT + r;
    size_t o = ((size_t)b * NROW + row) * H + hq * 4;
    float4 gv = *(const float4*)(gbuf + o);
    float4 ov = make_float4(fmaxf(acc[r][0] + gv.x, 0.f), fmaxf(acc[r][1] + gv.y, 0.f),
                            fmaxf(acc[r][2] + gv.z, 0.f), fmaxf(acc[r][3] + gv.w, 0.f));
    *(float4*)(out + o) = ov;
  }
}

// ---------------- zero-fill float4 buffer ----------------
__global__ __launch_bounds__(256) void k_zero(float4* __restrict__ p, int n4) {
  int i = blockIdx.x * 256 + threadIdx.x;
  if (i < n4) p[i] = make_float4(0.f, 0.f, 0.f, 0.f);
}

// ---------------- top-k pool: scores, select, gate, gather ----------------
// Kept set re-sorted by ascending original index (downstream is permutation-invariant).
template<int NN, int K>
__global__ __launch_bounds__(256) void k_topk(
    const float* __restrict__ x, const float* __restrict__ p,
    const int* __restrict__ prev_idx,
    float* __restrict__ xg, int* __restrict__ out_idx) {
  __shared__ float ys[NN];
  __shared__ int is[NN];
  __shared__ float ps[H];
  __shared__ float pns;
  const int tid = threadIdx.x;
  const int b = blockIdx.x;
  if (tid < H) ps[tid] = p[tid];
  __syncthreads();
  if (tid == 0) {
    float s = 0.f;
    for (int i = 0; i < H; ++i) s += ps[i] * ps[i];
    pns = 1.f / sqrtf(s);
  }
  __syncthreads();
  for (int i = tid; i < NN; i += 256) {
    const float* xr = x + ((size_t)b * NN + i) * H;
    float s = 0.f;
    #pragma unroll
    for (int f = 0; f < H; ++f) s += xr[f] * ps[f];
    ys[i] = s * pns;
    is[i] = i;
  }
  // bitonic sort: descending by value, ties -> lower index first (jax top_k)
  for (int k = 2; k <= NN; k <<= 1) {
    for (int j = k >> 1; j > 0; j >>= 1) {
      __syncthreads();
      for (int i = tid; i < NN; i += 256) {
        int ixj = i ^ j;
        if (ixj > i) {
          float v0 = ys[i], v1 = ys[ixj];
          int i0 = is[i], i1 = is[ixj];
          bool pre = (v1 > v0) || (v1 == v0 && i1 < i0);
          bool doswap = ((i & k) == 0) ? pre : !pre;
          if (doswap) { ys[i] = v1; ys[ixj] = v0; is[i] = i1; is[ixj] = i0; }
        }
      }
    }
  }
  // re-sort kept K by ascending original index (gather locality downstream)
  for (int k = 2; k <= K; k <<= 1) {
    for (int j = k >> 1; j > 0; j >>= 1) {
      __syncthreads();
      for (int i = tid; i < K; i += 256) {
        int ixj = i ^ j;
        if (ixj > i && ixj < K) {
          float v0 = ys[i], v1 = ys[ixj];
          int i0 = is[i], i1 = is[ixj];
          bool pre = (i1 < i0);
          bool doswap = ((i & k) == 0) ? pre : !pre;
          if (doswap) { ys[i] = v1; ys[ixj] = v0; is[i] = i1; is[ixj] = i0; }
        }
      }
    }
  }
  __syncthreads();
  for (int t = tid; t < K * H; t += 256) {
    int kk = t >> 5, f = t & 31;
    int loc = is[kk];
    float gate = 1.f / (1.f + expf(-ys[kk]));
    xg[((size_t)b * K + kk) * H + f] = x[((size_t)b * NN + loc) * H + f] * gate;
  }
  for (int t = tid; t < K; t += 256)
    out_idx[(size_t)b * K + t] = prev_idx ? prev_idx[(size_t)b * NN + is[t]] : is[t];
}

// ---------------- mean over nodes -> dense -> softmax ----------------
__global__ __launch_bounds__(128) void k_head(
    const float* __restrict__ xl3, const float* __restrict__ wd,
    const float* __restrict__ bd, float* __restrict__ out) {
  __shared__ float part[4][H];
  __shared__ float pooled[H];
  __shared__ float wds[H * NC];
  __shared__ float logits[NC];
  const int tid = threadIdx.x;
  const int b = blockIdx.x;
  for (int i = tid; i < H * NC; i += 128) wds[i] = wd[i];
  const int f = tid & 31, nq = tid >> 5;
  float s = 0.f;
  for (int n = nq * 32; n < nq * 32 + 32; ++n)
    s += xl3[((size_t)b * 128 + n) * H + f];
  part[nq][f] = s;
  __syncthreads();
  if (tid < H)
    pooled[tid] = (part[0][tid] + part[1][tid] + part[2][tid] + part[3][tid]) * (1.f / 128.f);
  __syncthreads();
  if (tid < NC) {
    float acc = bd[tid];
    for (int i = 0; i < H; ++i) acc += pooled[i] * wds[i * NC + tid];
    logits[tid] = acc;
  }
  __syncthreads();
  if (tid == 0) {
    float mx = logits[0];
    for (int i = 1; i < NC; ++i) mx = fmaxf(mx, logits[i]);
    float e[NC], se = 0.f;
    for (int i = 0; i < NC; ++i) { e[i] = expf(logits[i] - mx); se += e[i]; }
    float inv = 1.f / se;
    for (int i = 0; i < NC; ++i) out[(size_t)b * NC + i] = e[i] * inv;
  }
}

extern "C" void kernel_launch(void* const* d_in, const int* in_sizes, int n_in,
                              void* d_out, int out_size, void* d_ws, size_t ws_size,
                              hipStream_t stream) {
  (void)in_sizes; (void)n_in; (void)out_size; (void)ws_size;
  const float* x    = (const float*)d_in[0];
  const float* a    = (const float*)d_in[1];
  const float* w1_1 = (const float*)d_in[2];
  const float* w2_1 = (const float*)d_in[3];
  const float* b1   = (const float*)d_in[4];
  const float* w1_2 = (const float*)d_in[5];
  const float* w2_2 = (const float*)d_in[6];
  const float* b2   = (const float*)d_in[7];
  const float* w1_3 = (const float*)d_in[8];
  const float* w2_3 = (const float*)d_in[9];
  const float* b3   = (const float*)d_in[10];
  const float* pp   = (const float*)d_in[11];
  const float* wd   = (const float*)d_in[12];
  const float* bd   = (const float*)d_in[13];
  float* out = (float*)d_out;

  char* w = (char*)d_ws;
  auto take = [&](size_t bytes) { char* r = w; w += (bytes + 255) & ~(size_t)255; return r; };
  float* h1  = (float*)take((size_t)B * N0 * H * 4);   // reused as hf2 (scattered h2)
  float* g1  = (float*)take((size_t)B * N0 * H * 4);   // reused as hf3 (scattered h3)
  float* xl1 = (float*)take((size_t)B * N0 * H * 4);
  int*   id1 = (int*)  take((size_t)B * 256 * 4);
  float* xg1 = (float*)take((size_t)B * 256 * H * 4);
  float* g2  = (float*)take((size_t)B * 256 * H * 4);
  float* xl2 = (float*)take((size_t)B * 256 * H * 4);
  int*   id2 = (int*)  take((size_t)B * 128 * 4);
  float* xg2 = (float*)take((size_t)B * 128 * H * 4);
  float* g3  = (float*)take((size_t)B * 128 * H * 4);
  float* xl3 = (float*)take((size_t)B * 128 * H * 4);
  float* hf2 = h1;
  float* hf3 = g1;

  // Layer 1: h1 = x@w1, g1 = x@w2+b  (dense)
  k_xw<F0, 4, N0, false><<<dim3(B * N0 / 128), dim3(256), 0, stream>>>(
      x, w1_1, w2_1, b1, nullptr, h1, g1);
  // xl1 = relu(a @ h1 + g1)
  k_amm<512, 4><<<dim3(B, 4), dim3(256), 0, stream>>>(a, nullptr, h1, g1, xl1);
  // zero hf2+hf3 (h1,g1 contiguous in ws) now that layer 1 consumed them
  k_zero<<<dim3(2 * B * N0 * H / 4 / 256), dim3(256), 0, stream>>>(
      (float4*)h1, 2 * B * N0 * H / 4);
  // Pool 1
  k_topk<512, 256><<<dim3(B), dim3(256), 0, stream>>>(xl1, pp, nullptr, xg1, id1);
  // Layer 2: h2 scattered into hf2 at global node ids; g2 dense (kept order)
  k_xw<H, 4, 256, true><<<dim3(B * 256 / 128), dim3(256), 0, stream>>>(
      xg1, w1_2, w2_2, b2, id1, hf2, g2);
  // xl2 = relu(a[id1,:] @ hf2 + g2)   (full-width K, zero-padded columns)
  k_amm<256, 2><<<dim3(B, 4), dim3(256), 0, stream>>>(a, id1, hf2, g2, xl2);
  // Pool 2
  k_topk<256, 128><<<dim3(B), dim3(256), 0, stream>>>(xl2, pp, id1, xg2, id2);
  // Layer 3  (hf3 = g1 buffer: still all-zero outside scattered writes)
  k_xw<H, 4, 128, true><<<dim3(B * 128 / 128), dim3(256), 0, stream>>>(
      xg2, w1_3, w2_3, b3, id2, hf3, g3);
  k_amm<128, 1><<<dim3(B, 4), dim3(256), 0, stream>>>(a, id2, hf3, g3, xl3);
  // Head
  k_head<<<dim3(B), dim3(128), 0, stream>>>(xl3, wd, bd, out);
}

// Round 5
// 651.332 us; speedup vs baseline: 1.1434x; 1.1434x over previous
//
#include <hip/hip_runtime.h>
#include <cmath>

#define B 256
#define N0 512
#define F0 128
#define H 32
#define NC 16

// ---------------- x @ w1 -> h (optionally scattered) ; x @ w2 + b -> g ----------------
// block 256 = 8 h-threads (x4 h) x 32 row-groups (xRPT rows)
template<int F, int RPT, int NPB, bool SCATTER>
__global__ __launch_bounds__(256) void k_xw(
    const float* __restrict__ x, const float* __restrict__ w1,
    const float* __restrict__ w2, const float* __restrict__ bias,
    const int* __restrict__ sidx,
    float* __restrict__ h, float* __restrict__ g) {
  __shared__ float w1t[H][F + 4];
  __shared__ float w2t[H][F + 4];
  __shared__ float bs[H];
  const int tid = threadIdx.x;
  for (int i = tid; i < F * H; i += 256) {
    int f = i >> 5, hc = i & 31;
    w1t[hc][f] = w1[i];
    w2t[hc][f] = w2[i];
  }
  if (tid < H) bs[tid] = bias[tid];
  __syncthreads();
  const int hq = tid & 7;
  const int rq = tid >> 3;
  const size_t row0 = (size_t)blockIdx.x * (32 * RPT) + (size_t)rq * RPT;
  const float* xb = x + row0 * F;
  float acc1[RPT][4];
  float acc2[RPT][4];
  #pragma unroll
  for (int r = 0; r < RPT; ++r)
    for (int c = 0; c < 4; ++c) { acc1[r][c] = 0.f; acc2[r][c] = 0.f; }
  for (int f0 = 0; f0 < F; f0 += 4) {
    float4 w1v[4], w2v[4];
    #pragma unroll
    for (int hh = 0; hh < 4; ++hh) {
      w1v[hh] = *(const float4*)&w1t[hq * 4 + hh][f0];
      w2v[hh] = *(const float4*)&w2t[hq * 4 + hh][f0];
    }
    #pragma unroll
    for (int r = 0; r < RPT; ++r) {
      float4 xv = *(const float4*)(xb + (size_t)r * F + f0);
      #pragma unroll
      for (int hh = 0; hh < 4; ++hh) {
        acc1[r][hh] += xv.x * w1v[hh].x + xv.y * w1v[hh].y + xv.z * w1v[hh].z + xv.w * w1v[hh].w;
        acc2[r][hh] += xv.x * w2v[hh].x + xv.y * w2v[hh].y + xv.z * w2v[hh].z + xv.w * w2v[hh].w;
      }
    }
  }
  #pragma unroll
  for (int r = 0; r < RPT; ++r) {
    size_t row = row0 + r;
    size_t go = row * H + hq * 4;
    size_t ho;
    if (SCATTER) {
      int b = (int)(row / NPB);
      int gid = sidx[row];
      ho = ((size_t)b * N0 + gid) * H + hq * 4;
    } else {
      ho = go;
    }
    float4 hv = make_float4(acc1[r][0], acc1[r][1], acc1[r][2], acc1[r][3]);
    float4 gv = make_float4(acc2[r][0] + bs[hq * 4 + 0], acc2[r][1] + bs[hq * 4 + 1],
                            acc2[r][2] + bs[hq * 4 + 2], acc2[r][3] + bs[hq * 4 + 3]);
    *(float4*)(h + ho) = hv;
    *(float4*)(g + go) = gv;
  }
}

// ---------------- out = relu(A[rid,:] @ hf + g) ; K always = N0 (hf zero-padded) ----------
// R3-proven 2-barrier LDS staging; smaller tiles (RB=32*RPT) + bigger grid for TLP.
// a-tile stride 66 floats -> 2-way-max bank aliasing on float2 reads (free).
template<int NROW, int RPT>
__global__ __launch_bounds__(256) void k_amm(
    const float* __restrict__ a0, const int* __restrict__ rid,
    const float* __restrict__ hf, const float* __restrict__ gbuf,
    float* __restrict__ out) {
  constexpr int RB = 32 * RPT;   // rows per block
  constexpr int JC = 64;         // j per chunk
  constexpr int AS = JC + 2;     // a-tile stride (floats)
  __shared__ float atile[RB][AS];
  __shared__ float htile[JC][H];
  __shared__ int rowid[RB];
  const int tid = threadIdx.x;
  const int b = blockIdx.x;
  const int row0 = blockIdx.y * RB;
  for (int i = tid; i < RB; i += 256) {
    int row = row0 + i;
    rowid[i] = rid ? rid[(size_t)b * NROW + row] : row;
  }
  __syncthreads();
  const int hq = tid & 7;
  const int rq = tid >> 3;
  const int ar = tid >> 4;   // staging row-sub (0..15)
  const int ac = tid & 15;   // staging f4-col (0..15): 16x16B = 256B per row-seg
  const float* abase = a0 + (size_t)b * N0 * N0;
  float acc[RPT][4];
  #pragma unroll
  for (int r = 0; r < RPT; ++r) { acc[r][0] = acc[r][1] = acc[r][2] = acc[r][3] = 0.f; }
  for (int j0 = 0; j0 < N0; j0 += JC) {
    if (j0) __syncthreads();
    // stage h chunk (coalesced)
    {
      const float4* src = (const float4*)(hf + ((size_t)b * N0 + j0) * H);
      float4* dst = (float4*)htile;
      #pragma unroll
      for (int i = 0; i < JC * H / 4 / 256; ++i) dst[tid + i * 256] = src[tid + i * 256];
    }
    // stage a chunk (coalesced: 16 consecutive threads cover one row's 256B)
    #pragma unroll
    for (int i = 0; i < RB / 16; ++i) {
      int r = ar + i * 16;
      float4 v = *(const float4*)(abase + (size_t)rowid[r] * N0 + j0 + ac * 4);
      *(float2*)&atile[r][ac * 4] = make_float2(v.x, v.y);
      *(float2*)&atile[r][ac * 4 + 2] = make_float2(v.z, v.w);
    }
    __syncthreads();
    #pragma unroll 4
    for (int j = 0; j < JC; j += 4) {
      float4 hv[4];
      #pragma unroll
      for (int jj = 0; jj < 4; ++jj) hv[jj] = *(const float4*)&htile[j + jj][hq * 4];
      #pragma unroll
      for (int r = 0; r < RPT; ++r) {
        float2 a01 = *(const float2*)&atile[rq * RPT + r][j];
        float2 a23 = *(const float2*)&atile[rq * RPT + r][j + 2];
        acc[r][0] += a01.x * hv[0].x + a01.y * hv[1].x + a23.x * hv[2].x + a23.y * hv[3].x;
        acc[r][1] += a01.x * hv[0].y + a01.y * hv[1].y + a23.x * hv[2].y + a23.y * hv[3].y;
        acc[r][2] += a01.x * hv[0].z + a01.y * hv[1].z + a23.x * hv[2].z + a23.y * hv[3].z;
        acc[r][3] += a01.x * hv[0].w + a01.y * hv[1].w + a23.x * hv[2].w + a23.y * hv[3].w;
      }
    }
  }
  #pragma unroll
  for (int r = 0; r < RPT; ++r) {
    int row = row0 + rq * RPT + r;
    size_t o = ((size_t)b * NROW + row) * H + hq * 4;
    float4 gv = *(const float4*)(gbuf + o);
    float4 ov = make_float4(fmaxf(acc[r][0] + gv.x, 0.f), fmaxf(acc[r][1] + gv.y, 0.f),
                            fmaxf(acc[r][2] + gv.z, 0.f), fmaxf(acc[r][3] + gv.w, 0.f));
    *(float4*)(out + o) = ov;
  }
}

// ---------------- zero-fill float4 buffer ----------------
__global__ __launch_bounds__(256) void k_zero(float4* __restrict__ p, int n4) {
  int i = blockIdx.x * 256 + threadIdx.x;
  if (i < n4) p[i] = make_float4(0.f, 0.f, 0.f, 0.f);
}

// ---------------- top-k pool: scores, select, gate, gather ----------------
// Kept set re-sorted by ascending original index (downstream is permutation-invariant).
template<int NN, int K>
__global__ __launch_bounds__(256) void k_topk(
    const float* __restrict__ x, const float* __restrict__ p,
    const int* __restrict__ prev_idx,
    float* __restrict__ xg, int* __restrict__ out_idx) {
  __shared__ float ys[NN];
  __shared__ int is[NN];
  __shared__ float ps[H];
  __shared__ float pns;
  const int tid = threadIdx.x;
  const int b = blockIdx.x;
  if (tid < H) ps[tid] = p[tid];
  __syncthreads();
  if (tid == 0) {
    float s = 0.f;
    for (int i = 0; i < H; ++i) s += ps[i] * ps[i];
    pns = 1.f / sqrtf(s);
  }
  __syncthreads();
  for (int i = tid; i < NN; i += 256) {
    const float* xr = x + ((size_t)b * NN + i) * H;
    float s = 0.f;
    #pragma unroll
    for (int f = 0; f < H; ++f) s += xr[f] * ps[f];
    ys[i] = s * pns;
    is[i] = i;
  }
  // bitonic sort: descending by value, ties -> lower index first (jax top_k)
  for (int k = 2; k <= NN; k <<= 1) {
    for (int j = k >> 1; j > 0; j >>= 1) {
      __syncthreads();
      for (int i = tid; i < NN; i += 256) {
        int ixj = i ^ j;
        if (ixj > i) {
          float v0 = ys[i], v1 = ys[ixj];
          int i0 = is[i], i1 = is[ixj];
          bool pre = (v1 > v0) || (v1 == v0 && i1 < i0);
          bool doswap = ((i & k) == 0) ? pre : !pre;
          if (doswap) { ys[i] = v1; ys[ixj] = v0; is[i] = i1; is[ixj] = i0; }
        }
      }
    }
  }
  // re-sort kept K by ascending original index (gather locality downstream)
  for (int k = 2; k <= K; k <<= 1) {
    for (int j = k >> 1; j > 0; j >>= 1) {
      __syncthreads();
      for (int i = tid; i < K; i += 256) {
        int ixj = i ^ j;
        if (ixj > i && ixj < K) {
          float v0 = ys[i], v1 = ys[ixj];
          int i0 = is[i], i1 = is[ixj];
          bool pre = (i1 < i0);
          bool doswap = ((i & k) == 0) ? pre : !pre;
          if (doswap) { ys[i] = v1; ys[ixj] = v0; is[i] = i1; is[ixj] = i0; }
        }
      }
    }
  }
  __syncthreads();
  for (int t = tid; t < K * H; t += 256) {
    int kk = t >> 5, f = t & 31;
    int loc = is[kk];
    float gate = 1.f / (1.f + expf(-ys[kk]));
    xg[((size_t)b * K + kk) * H + f] = x[((size_t)b * NN + loc) * H + f] * gate;
  }
  for (int t = tid; t < K; t += 256)
    out_idx[(size_t)b * K + t] = prev_idx ? prev_idx[(size_t)b * NN + is[t]] : is[t];
}

// ---------------- mean over nodes -> dense -> softmax ----------------
__global__ __launch_bounds__(128) void k_head(
    const float* __restrict__ xl3, const float* __restrict__ wd,
    const float* __restrict__ bd, float* __restrict__ out) {
  __shared__ float part[4][H];
  __shared__ float pooled[H];
  __shared__ float wds[H * NC];
  __shared__ float logits[NC];
  const int tid = threadIdx.x;
  const int b = blockIdx.x;
  for (int i = tid; i < H * NC; i += 128) wds[i] = wd[i];
  const int f = tid & 31, nq = tid >> 5;
  float s = 0.f;
  for (int n = nq * 32; n < nq * 32 + 32; ++n)
    s += xl3[((size_t)b * 128 + n) * H + f];
  part[nq][f] = s;
  __syncthreads();
  if (tid < H)
    pooled[tid] = (part[0][tid] + part[1][tid] + part[2][tid] + part[3][tid]) * (1.f / 128.f);
  __syncthreads();
  if (tid < NC) {
    float acc = bd[tid];
    for (int i = 0; i < H; ++i) acc += pooled[i] * wds[i * NC + tid];
    logits[tid] = acc;
  }
  __syncthreads();
  if (tid == 0) {
    float mx = logits[0];
    for (int i = 1; i < NC; ++i) mx = fmaxf(mx, logits[i]);
    float e[NC], se = 0.f;
    for (int i = 0; i < NC; ++i) { e[i] = expf(logits[i] - mx); se += e[i]; }
    float inv = 1.f / se;
    for (int i = 0; i < NC; ++i) out[(size_t)b * NC + i] = e[i] * inv;
  }
}

extern "C" void kernel_launch(void* const* d_in, const int* in_sizes, int n_in,
                              void* d_out, int out_size, void* d_ws, size_t ws_size,
                              hipStream_t stream) {
  (void)in_sizes; (void)n_in; (void)out_size; (void)ws_size;
  const float* x    = (const float*)d_in[0];
  const float* a    = (const float*)d_in[1];
  const float* w1_1 = (const float*)d_in[2];
  const float* w2_1 = (const float*)d_in[3];
  const float* b1   = (const float*)d_in[4];
  const float* w1_2 = (const float*)d_in[5];
  const float* w2_2 = (const float*)d_in[6];
  const float* b2   = (const float*)d_in[7];
  const float* w1_3 = (const float*)d_in[8];
  const float* w2_3 = (const float*)d_in[9];
  const float* b3   = (const float*)d_in[10];
  const float* pp   = (const float*)d_in[11];
  const float* wd   = (const float*)d_in[12];
  const float* bd   = (const float*)d_in[13];
  float* out = (float*)d_out;

  char* w = (char*)d_ws;
  auto take = [&](size_t bytes) { char* r = w; w += (bytes + 255) & ~(size_t)255; return r; };
  float* h1  = (float*)take((size_t)B * N0 * H * 4);   // reused as hf2 (scattered h2)
  float* g1  = (float*)take((size_t)B * N0 * H * 4);   // reused as hf3 (scattered h3)
  float* xl1 = (float*)take((size_t)B * N0 * H * 4);
  int*   id1 = (int*)  take((size_t)B * 256 * 4);
  float* xg1 = (float*)take((size_t)B * 256 * H * 4);
  float* g2  = (float*)take((size_t)B * 256 * H * 4);
  float* xl2 = (float*)take((size_t)B * 256 * H * 4);
  int*   id2 = (int*)  take((size_t)B * 128 * 4);
  float* xg2 = (float*)take((size_t)B * 128 * H * 4);
  float* g3  = (float*)take((size_t)B * 128 * H * 4);
  float* xl3 = (float*)take((size_t)B * 128 * H * 4);
  float* hf2 = h1;
  float* hf3 = g1;

  // Layer 1: h1 = x@w1, g1 = x@w2+b  (dense)
  k_xw<F0, 2, N0, false><<<dim3(B * N0 / 64), dim3(256), 0, stream>>>(
      x, w1_1, w2_1, b1, nullptr, h1, g1);
  // xl1 = relu(a @ h1 + g1)   (RB=64, grid 2048 -> ~6 resident blocks/CU)
  k_amm<512, 2><<<dim3(B, 8), dim3(256), 0, stream>>>(a, nullptr, h1, g1, xl1);
  // zero hf2+hf3 (h1,g1 contiguous in ws) now that layer 1 consumed them
  k_zero<<<dim3(2 * B * N0 * H / 4 / 256), dim3(256), 0, stream>>>(
      (float4*)h1, 2 * B * N0 * H / 4);
  // Pool 1
  k_topk<512, 256><<<dim3(B), dim3(256), 0, stream>>>(xl1, pp, nullptr, xg1, id1);
  // Layer 2: h2 scattered into hf2 at global node ids; g2 dense (kept order)
  k_xw<H, 4, 256, true><<<dim3(B * 256 / 128), dim3(256), 0, stream>>>(
      xg1, w1_2, w2_2, b2, id1, hf2, g2);
  // xl2 = relu(a[id1,:] @ hf2 + g2)   (RB=32, grid 2048 -> ~8 resident blocks/CU)
  k_amm<256, 1><<<dim3(B, 8), dim3(256), 0, stream>>>(a, id1, hf2, g2, xl2);
  // Pool 2
  k_topk<256, 128><<<dim3(B), dim3(256), 0, stream>>>(xl2, pp, id1, xg2, id2);
  // Layer 3  (hf3 = g1 buffer: still all-zero outside scattered writes)
  k_xw<H, 4, 128, true><<<dim3(B * 128 / 128), dim3(256), 0, stream>>>(
      xg2, w1_3, w2_3, b3, id2, hf3, g3);
  k_amm<128, 1><<<dim3(B, 4), dim3(256), 0, stream>>>(a, id2, hf3, g3, xl3);
  // Head
  k_head<<<dim3(B), dim3(128), 0, stream>>>(xl3, wd, bd, out);
}

// Round 6
// 602.191 us; speedup vs baseline: 1.2367x; 1.0816x over previous
//
#include <hip/hip_runtime.h>
#include <cmath>

#define B 256
#define N0 512
#define F0 128
#define H 32
#define NC 16

typedef short v8s __attribute__((ext_vector_type(8)));
typedef float v4f __attribute__((ext_vector_type(4)));

__device__ inline ushort bf16_rne(float f) {
  unsigned u = __float_as_uint(f);
  unsigned r = (u + 0x7FFF + ((u >> 16) & 1)) >> 16;
  return (ushort)r;
}
__device__ inline float bf16_f(ushort s) { return __uint_as_float((unsigned)s << 16); }

// ---------------- x @ w1 -> h ; x @ w2 + b -> g  (dense, R5-proven) ----------------
template<int F, int RPT>
__global__ __launch_bounds__(256) void k_xw(
    const float* __restrict__ x, const float* __restrict__ w1,
    const float* __restrict__ w2, const float* __restrict__ bias,
    float* __restrict__ h, float* __restrict__ g) {
  __shared__ float w1t[H][F + 4];
  __shared__ float w2t[H][F + 4];
  __shared__ float bs[H];
  const int tid = threadIdx.x;
  for (int i = tid; i < F * H; i += 256) {
    int f = i >> 5, hc = i & 31;
    w1t[hc][f] = w1[i];
    w2t[hc][f] = w2[i];
  }
  if (tid < H) bs[tid] = bias[tid];
  __syncthreads();
  const int hq = tid & 7;
  const int rq = tid >> 3;
  const size_t row0 = (size_t)blockIdx.x * (32 * RPT) + (size_t)rq * RPT;
  const float* xb = x + row0 * F;
  float acc1[RPT][4];
  float acc2[RPT][4];
  #pragma unroll
  for (int r = 0; r < RPT; ++r)
    for (int c = 0; c < 4; ++c) { acc1[r][c] = 0.f; acc2[r][c] = 0.f; }
  for (int f0 = 0; f0 < F; f0 += 4) {
    float4 w1v[4], w2v[4];
    #pragma unroll
    for (int hh = 0; hh < 4; ++hh) {
      w1v[hh] = *(const float4*)&w1t[hq * 4 + hh][f0];
      w2v[hh] = *(const float4*)&w2t[hq * 4 + hh][f0];
    }
    #pragma unroll
    for (int r = 0; r < RPT; ++r) {
      float4 xv = *(const float4*)(xb + (size_t)r * F + f0);
      #pragma unroll
      for (int hh = 0; hh < 4; ++hh) {
        acc1[r][hh] += xv.x * w1v[hh].x + xv.y * w1v[hh].y + xv.z * w1v[hh].z + xv.w * w1v[hh].w;
        acc2[r][hh] += xv.x * w2v[hh].x + xv.y * w2v[hh].y + xv.z * w2v[hh].z + xv.w * w2v[hh].w;
      }
    }
  }
  #pragma unroll
  for (int r = 0; r < RPT; ++r) {
    size_t o = (row0 + r) * H + hq * 4;
    float4 hv = make_float4(acc1[r][0], acc1[r][1], acc1[r][2], acc1[r][3]);
    float4 gv = make_float4(acc2[r][0] + bs[hq * 4 + 0], acc2[r][1] + bs[hq * 4 + 1],
                            acc2[r][2] + bs[hq * 4 + 2], acc2[r][3] + bs[hq * 4 + 3]);
    *(float4*)(h + o) = hv;
    *(float4*)(g + o) = gv;
  }
}

// ------------- dense transpose + bf16 split: h[B][512][32] -> hT hi/lo [B][32][512] -------------
__global__ __launch_bounds__(256) void k_trans_d(
    const float* __restrict__ hsrc, ushort* __restrict__ hTh, ushort* __restrict__ hTl) {
  __shared__ ushort thi[H][72];
  __shared__ ushort tlo[H][72];
  const int tid = threadIdx.x;
  const int b = blockIdx.x;
  const int jr = tid >> 2, kq = tid & 3;      // read: row-in-chunk, col-group
  const int hh = tid >> 3, seg = tid & 7;     // write: h-row, col-seg
  for (int j0 = 0; j0 < N0; j0 += 64) {
    if (j0) __syncthreads();
    const float* src = hsrc + (((size_t)b * N0) + j0 + jr) * H + kq * 8;
    float4 v0 = *(const float4*)src;
    float4 v1 = *(const float4*)(src + 4);
    float vv[8] = {v0.x, v0.y, v0.z, v0.w, v1.x, v1.y, v1.z, v1.w};
    #pragma unroll
    for (int i = 0; i < 8; ++i) {
      ushort hi = bf16_rne(vv[i]);
      thi[kq * 8 + i][jr] = hi;
      tlo[kq * 8 + i][jr] = bf16_rne(vv[i] - bf16_f(hi));
    }
    __syncthreads();
    size_t o = ((size_t)b * H + hh) * N0 + j0 + seg * 8;
    *(uint4*)&hTh[o] = *(const uint4*)&thi[hh][seg * 8];
    *(uint4*)&hTl[o] = *(const uint4*)&tlo[hh][seg * 8];
  }
}

// ------------- scatter transpose + split: hd[B][K][32], gid -> hT[32][gid] (pre-zeroed) -------------
template<int K>
__global__ __launch_bounds__(256) void k_trans_s(
    const float* __restrict__ hd, const int* __restrict__ idx,
    ushort* __restrict__ hTh, ushort* __restrict__ hTl) {
  const int tid = threadIdx.x;
  const int b = blockIdx.x;
  for (int t = tid; t < K * 4; t += 256) {
    int row = t >> 2, kq = t & 3;
    int gid = idx[(size_t)b * K + row];
    const float* src = hd + (((size_t)b * K) + row) * H + kq * 8;
    float4 v0 = *(const float4*)src;
    float4 v1 = *(const float4*)(src + 4);
    float vv[8] = {v0.x, v0.y, v0.z, v0.w, v1.x, v1.y, v1.z, v1.w};
    #pragma unroll
    for (int i = 0; i < 8; ++i) {
      ushort hi = bf16_rne(vv[i]);
      size_t o = ((size_t)b * H + kq * 8 + i) * N0 + gid;
      hTh[o] = hi;
      hTl[o] = bf16_rne(vv[i] - bf16_f(hi));
    }
  }
}

// ---------------- MFMA amm: out = relu(A[rid,:] @ h + g), split-bf16, K=512 ----------------
// block 256 = 4 waves; wave w: rows [w*16, w*16+16) x 32 h cols. KC=32 per chunk.
template<int NROW>
__global__ __launch_bounds__(256) void k_ammx(
    const float* __restrict__ a0, const int* __restrict__ rid,
    const ushort* __restrict__ hTh, const ushort* __restrict__ hTl,
    const float* __restrict__ g, float* __restrict__ out) {
  constexpr int RB = 64;
  constexpr int KC = 32;
  constexpr int ASP = KC + 8;   // 40: keeps b128 frag reads 16B-aligned
  __shared__ ushort ah[RB][ASP];
  __shared__ ushort al[RB][ASP];
  __shared__ ushort bh[H][ASP];
  __shared__ ushort bl[H][ASP];
  __shared__ int rowid[RB];
  const int tid = threadIdx.x;
  const int b = blockIdx.x;
  const int row0 = blockIdx.y * RB;
  if (tid < RB) rowid[tid] = rid ? rid[(size_t)b * NROW + row0 + tid] : row0 + tid;
  __syncthreads();
  const int wave = tid >> 6, lane = tid & 63;
  const int m = lane & 15, quad = lane >> 4;
  const int sr = tid >> 2, skq = tid & 3;     // A staging: row, col-group
  const int shh = tid >> 3, sseg = tid & 7;   // B staging: h-row, seg
  const float* abase = a0 + (size_t)b * N0 * N0;
  const ushort* bhsrc = hTh + ((size_t)b * H + shh) * N0 + sseg * 4;
  const ushort* blsrc = hTl + ((size_t)b * H + shh) * N0 + sseg * 4;
  v4f acc0 = {0.f, 0.f, 0.f, 0.f};
  v4f acc1 = {0.f, 0.f, 0.f, 0.f};
  for (int k0 = 0; k0 < N0; k0 += KC) {
    if (k0) __syncthreads();
    // stage A: 64 rows x 32 k fp32 -> bf16 hi/lo
    {
      const float* ap = abase + (size_t)rowid[sr] * N0 + k0 + skq * 4;
      float4 v0 = *(const float4*)ap;
      float4 v1 = *(const float4*)(ap + 16);
      ushort4 h0, l0, h1, l1;
      h0.x = bf16_rne(v0.x); l0.x = bf16_rne(v0.x - bf16_f(h0.x));
      h0.y = bf16_rne(v0.y); l0.y = bf16_rne(v0.y - bf16_f(h0.y));
      h0.z = bf16_rne(v0.z); l0.z = bf16_rne(v0.z - bf16_f(h0.z));
      h0.w = bf16_rne(v0.w); l0.w = bf16_rne(v0.w - bf16_f(h0.w));
      h1.x = bf16_rne(v1.x); l1.x = bf16_rne(v1.x - bf16_f(h1.x));
      h1.y = bf16_rne(v1.y); l1.y = bf16_rne(v1.y - bf16_f(h1.y));
      h1.z = bf16_rne(v1.z); l1.z = bf16_rne(v1.z - bf16_f(h1.z));
      h1.w = bf16_rne(v1.w); l1.w = bf16_rne(v1.w - bf16_f(h1.w));
      *(ushort4*)&ah[sr][skq * 4] = h0;      *(ushort4*)&al[sr][skq * 4] = l0;
      *(ushort4*)&ah[sr][skq * 4 + 16] = h1; *(ushort4*)&al[sr][skq * 4 + 16] = l1;
    }
    // stage B: 32 h x 32 k bf16 hi/lo (pre-split in global)
    {
      *(ushort4*)&bh[shh][sseg * 4] = *(const ushort4*)(bhsrc + k0);
      *(ushort4*)&bl[shh][sseg * 4] = *(const ushort4*)(blsrc + k0);
    }
    __syncthreads();
    const int arow = wave * 16 + m;
    v8s Ah = *(const v8s*)&ah[arow][quad * 8];
    v8s Al = *(const v8s*)&al[arow][quad * 8];
    v8s Bh0 = *(const v8s*)&bh[m][quad * 8];
    v8s Bh1 = *(const v8s*)&bh[16 + m][quad * 8];
    v8s Bl0 = *(const v8s*)&bl[m][quad * 8];
    v8s Bl1 = *(const v8s*)&bl[16 + m][quad * 8];
    acc0 = __builtin_amdgcn_mfma_f32_16x16x32_bf16(Ah, Bh0, acc0, 0, 0, 0);
    acc1 = __builtin_amdgcn_mfma_f32_16x16x32_bf16(Ah, Bh1, acc1, 0, 0, 0);
    acc0 = __builtin_amdgcn_mfma_f32_16x16x32_bf16(Al, Bh0, acc0, 0, 0, 0);
    acc1 = __builtin_amdgcn_mfma_f32_16x16x32_bf16(Al, Bh1, acc1, 0, 0, 0);
    acc0 = __builtin_amdgcn_mfma_f32_16x16x32_bf16(Ah, Bl0, acc0, 0, 0, 0);
    acc1 = __builtin_amdgcn_mfma_f32_16x16x32_bf16(Ah, Bl1, acc1, 0, 0, 0);
  }
  // epilogue: D col = lane&15, row = quad*4 + reg
  #pragma unroll
  for (int reg = 0; reg < 4; ++reg) {
    int row = row0 + wave * 16 + quad * 4 + reg;
    size_t o0 = ((size_t)b * NROW + row) * H + m;
    size_t o1 = o0 + 16;
    float v0 = acc0[reg] + g[o0];
    float v1 = acc1[reg] + g[o1];
    out[o0] = fmaxf(v0, 0.f);
    out[o1] = fmaxf(v1, 0.f);
  }
}

// ---------------- zero-fill float4 buffer ----------------
__global__ __launch_bounds__(256) void k_zero(float4* __restrict__ p, int n4) {
  int i = blockIdx.x * 256 + threadIdx.x;
  if (i < n4) p[i] = make_float4(0.f, 0.f, 0.f, 0.f);
}

// ---------------- top-k pool (R5-proven) ----------------
template<int NN, int K>
__global__ __launch_bounds__(256) void k_topk(
    const float* __restrict__ x, const float* __restrict__ p,
    const int* __restrict__ prev_idx,
    float* __restrict__ xg, int* __restrict__ out_idx) {
  __shared__ float ys[NN];
  __shared__ int is[NN];
  __shared__ float ps[H];
  __shared__ float pns;
  const int tid = threadIdx.x;
  const int b = blockIdx.x;
  if (tid < H) ps[tid] = p[tid];
  __syncthreads();
  if (tid == 0) {
    float s = 0.f;
    for (int i = 0; i < H; ++i) s += ps[i] * ps[i];
    pns = 1.f / sqrtf(s);
  }
  __syncthreads();
  for (int i = tid; i < NN; i += 256) {
    const float* xr = x + ((size_t)b * NN + i) * H;
    float s = 0.f;
    #pragma unroll
    for (int f = 0; f < H; ++f) s += xr[f] * ps[f];
    ys[i] = s * pns;
    is[i] = i;
  }
  for (int k = 2; k <= NN; k <<= 1) {
    for (int j = k >> 1; j > 0; j >>= 1) {
      __syncthreads();
      for (int i = tid; i < NN; i += 256) {
        int ixj = i ^ j;
        if (ixj > i) {
          float v0 = ys[i], v1 = ys[ixj];
          int i0 = is[i], i1 = is[ixj];
          bool pre = (v1 > v0) || (v1 == v0 && i1 < i0);
          bool doswap = ((i & k) == 0) ? pre : !pre;
          if (doswap) { ys[i] = v1; ys[ixj] = v0; is[i] = i1; is[ixj] = i0; }
        }
      }
    }
  }
  for (int k = 2; k <= K; k <<= 1) {
    for (int j = k >> 1; j > 0; j >>= 1) {
      __syncthreads();
      for (int i = tid; i < K; i += 256) {
        int ixj = i ^ j;
        if (ixj > i && ixj < K) {
          float v0 = ys[i], v1 = ys[ixj];
          int i0 = is[i], i1 = is[ixj];
          bool pre = (i1 < i0);
          bool doswap = ((i & k) == 0) ? pre : !pre;
          if (doswap) { ys[i] = v1; ys[ixj] = v0; is[i] = i1; is[ixj] = i0; }
        }
      }
    }
  }
  __syncthreads();
  for (int t = tid; t < K * H; t += 256) {
    int kk = t >> 5, f = t & 31;
    int loc = is[kk];
    float gate = 1.f / (1.f + expf(-ys[kk]));
    xg[((size_t)b * K + kk) * H + f] = x[((size_t)b * NN + loc) * H + f] * gate;
  }
  for (int t = tid; t < K; t += 256)
    out_idx[(size_t)b * K + t] = prev_idx ? prev_idx[(size_t)b * NN + is[t]] : is[t];
}

// ---------------- mean over nodes -> dense -> softmax ----------------
__global__ __launch_bounds__(128) void k_head(
    const float* __restrict__ xl3, const float* __restrict__ wd,
    const float* __restrict__ bd, float* __restrict__ out) {
  __shared__ float part[4][H];
  __shared__ float pooled[H];
  __shared__ float wds[H * NC];
  __shared__ float logits[NC];
  const int tid = threadIdx.x;
  const int b = blockIdx.x;
  for (int i = tid; i < H * NC; i += 128) wds[i] = wd[i];
  const int f = tid & 31, nq = tid >> 5;
  float s = 0.f;
  for (int n = nq * 32; n < nq * 32 + 32; ++n)
    s += xl3[((size_t)b * 128 + n) * H + f];
  part[nq][f] = s;
  __syncthreads();
  if (tid < H)
    pooled[tid] = (part[0][tid] + part[1][tid] + part[2][tid] + part[3][tid]) * (1.f / 128.f);
  __syncthreads();
  if (tid < NC) {
    float acc = bd[tid];
    for (int i = 0; i < H; ++i) acc += pooled[i] * wds[i * NC + tid];
    logits[tid] = acc;
  }
  __syncthreads();
  if (tid == 0) {
    float mx = logits[0];
    for (int i = 1; i < NC; ++i) mx = fmaxf(mx, logits[i]);
    float e[NC], se = 0.f;
    for (int i = 0; i < NC; ++i) { e[i] = expf(logits[i] - mx); se += e[i]; }
    float inv = 1.f / se;
    for (int i = 0; i < NC; ++i) out[(size_t)b * NC + i] = e[i] * inv;
  }
}

extern "C" void kernel_launch(void* const* d_in, const int* in_sizes, int n_in,
                              void* d_out, int out_size, void* d_ws, size_t ws_size,
                              hipStream_t stream) {
  (void)in_sizes; (void)n_in; (void)out_size; (void)ws_size;
  const float* x    = (const float*)d_in[0];
  const float* a    = (const float*)d_in[1];
  const float* w1_1 = (const float*)d_in[2];
  const float* w2_1 = (const float*)d_in[3];
  const float* b1   = (const float*)d_in[4];
  const float* w1_2 = (const float*)d_in[5];
  const float* w2_2 = (const float*)d_in[6];
  const float* b2   = (const float*)d_in[7];
  const float* w1_3 = (const float*)d_in[8];
  const float* w2_3 = (const float*)d_in[9];
  const float* b3   = (const float*)d_in[10];
  const float* pp   = (const float*)d_in[11];
  const float* wd   = (const float*)d_in[12];
  const float* bd   = (const float*)d_in[13];
  float* out = (float*)d_out;

  char* w = (char*)d_ws;
  auto take = [&](size_t bytes) { char* r = w; w += (bytes + 255) & ~(size_t)255; return r; };
  float*  h1  = (float*) take((size_t)B * N0 * H * 4);
  float*  g1  = (float*) take((size_t)B * N0 * H * 4);
  ushort* hTh = (ushort*)take((size_t)B * H * N0 * 2);
  ushort* hTl = (ushort*)take((size_t)B * H * N0 * 2);   // contiguous after hTh
  float*  xl1 = (float*) take((size_t)B * N0 * H * 4);
  int*    id1 = (int*)   take((size_t)B * 256 * 4);
  float*  xg1 = (float*) take((size_t)B * 256 * H * 4);
  float*  h2  = (float*) take((size_t)B * 256 * H * 4);
  float*  g2  = (float*) take((size_t)B * 256 * H * 4);
  float*  xl2 = (float*) take((size_t)B * 256 * H * 4);
  int*    id2 = (int*)   take((size_t)B * 128 * 4);
  float*  xg2 = (float*) take((size_t)B * 128 * H * 4);
  float*  h3  = (float*) take((size_t)B * 128 * H * 4);
  float*  g3  = (float*) take((size_t)B * 128 * H * 4);
  float*  xl3 = (float*) take((size_t)B * 128 * H * 4);
  const int hT4 = (int)((size_t)B * H * N0 * 2 * 2 / 16);  // both hi+lo, in float4s

  // Layer 1
  k_xw<F0, 2><<<dim3(B * N0 / 64), dim3(256), 0, stream>>>(x, w1_1, w2_1, b1, h1, g1);
  k_trans_d<<<dim3(B), dim3(256), 0, stream>>>(h1, hTh, hTl);
  k_ammx<512><<<dim3(B, 8), dim3(256), 0, stream>>>(a, nullptr, hTh, hTl, g1, xl1);
  // Pool 1
  k_topk<512, 256><<<dim3(B), dim3(256), 0, stream>>>(xl1, pp, nullptr, xg1, id1);
  // Layer 2
  k_xw<H, 4><<<dim3(B * 256 / 128), dim3(256), 0, stream>>>(xg1, w1_2, w2_2, b2, h2, g2);
  k_zero<<<dim3((hT4 + 255) / 256), dim3(256), 0, stream>>>((float4*)hTh, hT4);
  k_trans_s<256><<<dim3(B), dim3(256), 0, stream>>>(h2, id1, hTh, hTl);
  k_ammx<256><<<dim3(B, 4), dim3(256), 0, stream>>>(a, id1, hTh, hTl, g2, xl2);
  // Pool 2
  k_topk<256, 128><<<dim3(B), dim3(256), 0, stream>>>(xl2, pp, id1, xg2, id2);
  // Layer 3
  k_xw<H, 4><<<dim3(B * 128 / 128), dim3(256), 0, stream>>>(xg2, w1_3, w2_3, b3, h3, g3);
  k_zero<<<dim3((hT4 + 255) / 256), dim3(256), 0, stream>>>((float4*)hTh, hT4);
  k_trans_s<128><<<dim3(B), dim3(256), 0, stream>>>(h3, id2, hTh, hTl);
  k_ammx<128><<<dim3(B, 2), dim3(256), 0, stream>>>(a, id2, hTh, hTl, g3, xl3);
  // Head
  k_head<<<dim3(B), dim3(128), 0, stream>>>(xl3, wd, bd, out);
}